// Round 2
// baseline (528.291 us; speedup 1.0000x reference)
//
#include <hip/hip_runtime.h>
#include <stdint.h>

typedef unsigned short u16;
typedef __attribute__((ext_vector_type(8))) short bf16x8;
typedef __attribute__((ext_vector_type(4))) float f32x4;

__device__ __forceinline__ u16 f2b(float f) {
  uint32_t u = __float_as_uint(f);
  u += 0x7fffu + ((u >> 16) & 1u);
  return (u16)(u >> 16);
}
__device__ __forceinline__ float b2f(u16 h) {
  return __uint_as_float(((uint32_t)h) << 16);
}

__device__ __forceinline__ void gload_lds16(const u16* g, u16* l) {
  __builtin_amdgcn_global_load_lds(
      (const __attribute__((address_space(1))) void*)g,
      (__attribute__((address_space(3))) void*)l, 16, 0, 0);
}

// ---------------- GEMM: C[m,n] = sum_k A[m,k] * Bt[n,k] ------------------
// A: [M,K] bf16 row-major (lda), Bt: [N,K] bf16 row-major (ldb).
// 128x128 tile, BK=32, 4 waves each computing 64x64 via 4x4 MFMA 16x16x32.
// blockIdx.z encodes (part, batch): batch = z&7, part = z>>3 (8 batches always).
// For split-K: K is the PER-PART length; C += part*pStride (fp32 partials).
// LDS XOR swizzle: physical chunk p = logical c ^ ((row>>1)&3), applied at both
// staging (via global source col) and fragment read.
enum { EPI_BF16 = 0, EPI_F32 = 1, EPI_RELU_BF16 = 2 };

template <int EPI>
__global__ __launch_bounds__(256, 2) void gemm_nt(
    const u16* __restrict__ A, size_t sA, int lda,
    const u16* __restrict__ B, size_t sB, int ldb,
    void* __restrict__ C, size_t sC, int ldc, int K, size_t pStride) {
  __shared__ __align__(16) u16 As[128 * 32];
  __shared__ __align__(16) u16 Bs[128 * 32];
  const int t = threadIdx.x;
  const int batch = blockIdx.z & 7, part = blockIdx.z >> 3;
  const int m0 = blockIdx.y * 128, n0 = blockIdx.x * 128;
  const int koff = part * K;
  const u16* Ab = A + (size_t)batch * sA + (size_t)m0 * lda + koff;
  const u16* Bb = B + (size_t)batch * sB + (size_t)n0 * ldb + koff;
  // staging: thread t stages 16B at LDS slot t*16B = (row = t>>2, phys chunk t&3)
  // swizzle: that slot holds logical chunk (t&3) ^ ((t>>3)&3) of row t>>2
  const int ar0 = t >> 2;
  const int ar1 = ar0 + 64;
  const int ac0 = (((t & 3) ^ ((t >> 3) & 3)) << 3);
  const int w = t >> 6, lane = t & 63;
  const int wm = (w >> 1) << 6, wn = (w & 1) << 6;
  const int qd = lane >> 4, l16 = lane & 15;
  const int pc8 = ((qd ^ ((l16 >> 1) & 3)) << 3);  // phys chunk * 8 for reads

  f32x4 acc[4][4];
#pragma unroll
  for (int i = 0; i < 4; i++)
#pragma unroll
    for (int j = 0; j < 4; j++) acc[i][j] = (f32x4)0.0f;

  for (int k0 = 0; k0 < K; k0 += 32) {
    gload_lds16(Ab + (size_t)ar0 * lda + (k0 + ac0), As + t * 8);
    gload_lds16(Ab + (size_t)ar1 * lda + (k0 + ac0), As + (t + 256) * 8);
    gload_lds16(Bb + (size_t)ar0 * ldb + (k0 + ac0), Bs + t * 8);
    gload_lds16(Bb + (size_t)ar1 * ldb + (k0 + ac0), Bs + (t + 256) * 8);
    __syncthreads();  // drains vmcnt before barrier
    bf16x8 af[4], bfr[4];
#pragma unroll
    for (int i = 0; i < 4; i++)
      af[i] = *(const bf16x8*)(As + (wm + i * 16 + l16) * 32 + pc8);
#pragma unroll
    for (int i = 0; i < 4; i++)
      bfr[i] = *(const bf16x8*)(Bs + (wn + i * 16 + l16) * 32 + pc8);
#pragma unroll
    for (int mi = 0; mi < 4; mi++)
#pragma unroll
      for (int ni = 0; ni < 4; ni++)
        acc[mi][ni] = __builtin_amdgcn_mfma_f32_16x16x32_bf16(
            af[mi], bfr[ni], acc[mi][ni], 0, 0, 0);
    __syncthreads();
  }

  // C/D layout: col = lane&15, row = (lane>>4)*4 + r  (m89-verified)
  const size_t cbase = (size_t)part * pStride + (size_t)batch * sC;
#pragma unroll
  for (int mi = 0; mi < 4; mi++) {
#pragma unroll
    for (int ni = 0; ni < 4; ni++) {
      const int col = n0 + wn + ni * 16 + l16;
#pragma unroll
      for (int r = 0; r < 4; r++) {
        const int row = m0 + wm + mi * 16 + qd * 4 + r;
        const float v = acc[mi][ni][r];
        if (EPI == EPI_F32) {
          ((float*)C)[cbase + (size_t)row * ldc + col] = v;
        } else if (EPI == EPI_RELU_BF16) {
          ((u16*)C)[cbase + (size_t)row * ldc + col] = f2b(fmaxf(v, 0.0f));
        } else {
          ((u16*)C)[cbase + (size_t)row * ldc + col] = f2b(v);
        }
      }
    }
  }
}

// out[i] = bf16(sum over 4 split-K fp32 partials), float4-vectorized
__global__ __launch_bounds__(256) void reduce4_bf16(const float* __restrict__ P,
                                                    u16* __restrict__ out) {
  const size_t i = (size_t)blockIdx.x * 256 + threadIdx.x;  // float4 index
  const float4* p = (const float4*)P;
  float4 a = p[i];
  float4 b = p[i + 1048576];
  float4 c = p[i + 2097152];
  float4 d = p[i + 3145728];
  ushort4 o = make_ushort4(f2b(a.x + b.x + c.x + d.x), f2b(a.y + b.y + c.y + d.y),
                           f2b(a.z + b.z + c.z + d.z), f2b(a.w + b.w + c.w + d.w));
  *(ushort4*)(out + (i << 2)) = o;
}

// ---------------- aux kernels ------------------
__global__ __launch_bounds__(256) void cast_x_to_h(const float* __restrict__ x,
                                                   u16* __restrict__ h, int total4) {
  int i = blockIdx.x * blockDim.x + threadIdx.x;
  if (i >= total4) return;
  const float4 f = ((const float4*)x)[i];
  int e = i << 2;
  int row = e >> 9, col = e & 511;
  ushort4 o = make_ushort4(f2b(f.x), f2b(f.y), f2b(f.z), f2b(f.w));
  *(ushort4*)(h + ((size_t)row << 10) + col) = o;
}

__global__ __launch_bounds__(256) void cast_bf16(const float* __restrict__ in,
                                                 u16* __restrict__ out, int total4) {
  int i = blockIdx.x * blockDim.x + threadIdx.x;
  if (i >= total4) return;
  const float4 f = ((const float4*)in)[i];
  ushort4 o = make_ushort4(f2b(f.x), f2b(f.y), f2b(f.z), f2b(f.w));
  *(ushort4*)(out + ((size_t)i << 2)) = o;
}

// WT[c][r] = bf16(W[r][c]);  W: [R,Cn] fp32
__global__ void transpose_cast_w(const float* __restrict__ W, u16* __restrict__ WT,
                                 int R, int Cn) {
  __shared__ float tile[32][33];
  int c0 = blockIdx.x * 32, r0 = blockIdx.y * 32;
  int tx = threadIdx.x, ty = threadIdx.y;
  for (int i = ty; i < 32; i += 8) tile[i][tx] = W[(size_t)(r0 + i) * Cn + c0 + tx];
  __syncthreads();
  for (int i = ty; i < 32; i += 8) WT[(size_t)(c0 + i) * R + r0 + tx] = f2b(tile[tx][i]);
}

// vT[c][s] = v[s][c]; per batch, v: [4096,512] bf16
__global__ void transpose_v(const u16* __restrict__ v, u16* __restrict__ vT) {
  __shared__ u16 tile[64][65];
  const int s0 = blockIdx.x * 64, c0 = blockIdx.y * 64;
  const u16* vb = v + (size_t)blockIdx.z * 4096 * 512;
  u16* vTb = vT + (size_t)blockIdx.z * 4096 * 512;
  const int tx = threadIdx.x, ty = threadIdx.y;
  for (int i = ty; i < 64; i += 4) tile[i][tx] = vb[(size_t)(s0 + i) * 512 + c0 + tx];
  __syncthreads();
  for (int i = ty; i < 64; i += 4) vTb[(size_t)(c0 + i) * 4096 + s0 + tx] = tile[tx][i];
}

// out[row] = sum_c X[row][c]^2   (X bf16, 512 cols, one wave per row)
__global__ __launch_bounds__(256) void rowsumsq(const u16* __restrict__ X,
                                                float* __restrict__ out) {
  const int w = threadIdx.x >> 6, lane = threadIdx.x & 63;
  const size_t row = (size_t)blockIdx.x * 4 + w;
  const u16* xr = X + row * 512 + lane * 8;
  float s = 0.f;
#pragma unroll
  for (int i = 0; i < 8; i++) { float v = b2f(xr[i]); s += v * v; }
#pragma unroll
  for (int off = 32; off; off >>= 1) s += __shfl_xor(s, off);
  if (lane == 0) out[row] = s;
}

// in-place: row of bf16 qk -> softmax(sqrt(max(q2+k2-2qk,0))) as bf16
__global__ __launch_bounds__(256) void softmax_inplace(u16* __restrict__ qk,
                                                       const float* __restrict__ q2,
                                                       const float* __restrict__ k2) {
  const size_t row = blockIdx.x;  // [0, N*L)
  const int bz = (int)(row >> 10);
  u16* dr = qk + row * 4096;
  const float* k2b = k2 + ((size_t)bz << 12);
  const float q2r = q2[row];
  const int t = threadIdx.x;
  float v[16];
  float mx = -1e30f;
#pragma unroll
  for (int i = 0; i < 16; i++) {
    const int c = i * 256 + t;
    const float qkv = b2f(dr[c]);
    v[i] = sqrtf(fmaxf(q2r + k2b[c] - 2.0f * qkv, 0.0f));
    mx = fmaxf(mx, v[i]);
  }
#pragma unroll
  for (int off = 32; off; off >>= 1) mx = fmaxf(mx, __shfl_xor(mx, off));
  __shared__ float red[4], red2[4];
  if ((t & 63) == 0) red[t >> 6] = mx;
  __syncthreads();
  mx = fmaxf(fmaxf(red[0], red[1]), fmaxf(red[2], red[3]));
  float s = 0.f;
#pragma unroll
  for (int i = 0; i < 16; i++) { v[i] = __expf(v[i] - mx); s += v[i]; }
#pragma unroll
  for (int off = 32; off; off >>= 1) s += __shfl_xor(s, off);
  if ((t & 63) == 0) red2[t >> 6] = s;
  __syncthreads();
  s = red2[0] + red2[1] + red2[2] + red2[3];
  const float inv = 1.0f / s;
#pragma unroll
  for (int i = 0; i < 16; i++) dr[i * 256 + t] = f2b(v[i] * inv);
}

// h[row][512..1023] = bf16(LN(mm[row]; g,b)); 128 thr/row, float4 each
__global__ __launch_bounds__(128) void ln_to_h(const float* __restrict__ mm,
                                               const float* __restrict__ g,
                                               const float* __restrict__ b,
                                               u16* __restrict__ h) {
  const size_t row = blockIdx.x;
  const int t = threadIdx.x;
  const float4 f = ((const float4*)(mm + row * 512))[t];
  float s = f.x + f.y + f.z + f.w;
  float sq = f.x * f.x + f.y * f.y + f.z * f.z + f.w * f.w;
#pragma unroll
  for (int off = 32; off; off >>= 1) { s += __shfl_xor(s, off); sq += __shfl_xor(sq, off); }
  __shared__ float rs_[2], rq_[2];
  if ((t & 63) == 0) { rs_[t >> 6] = s; rq_[t >> 6] = sq; }
  __syncthreads();
  s = rs_[0] + rs_[1]; sq = rq_[0] + rq_[1];
  const float mu = s * (1.0f / 512.0f);
  const float rstd = rsqrtf(sq * (1.0f / 512.0f) - mu * mu + 1e-5f);
  const float4 gv = ((const float4*)g)[t], bv = ((const float4*)b)[t];
  ushort4 o = make_ushort4(f2b((f.x - mu) * rstd * gv.x + bv.x),
                           f2b((f.y - mu) * rstd * gv.y + bv.y),
                           f2b((f.z - mu) * rstd * gv.z + bv.z),
                           f2b((f.w - mu) * rstd * gv.w + bv.w));
  *(ushort4*)(h + (row << 10) + 512 + (t << 2)) = o;
}

// out[row] = x[row] + LN(m2[row]; g,b)
__global__ __launch_bounds__(128) void ln_residual(const float* __restrict__ m2,
                                                   const float* __restrict__ x,
                                                   const float* __restrict__ g,
                                                   const float* __restrict__ b,
                                                   float* __restrict__ out) {
  const size_t row = blockIdx.x;
  const int t = threadIdx.x;
  const float4 f = ((const float4*)(m2 + row * 512))[t];
  float s = f.x + f.y + f.z + f.w;
  float sq = f.x * f.x + f.y * f.y + f.z * f.z + f.w * f.w;
#pragma unroll
  for (int off = 32; off; off >>= 1) { s += __shfl_xor(s, off); sq += __shfl_xor(sq, off); }
  __shared__ float rs_[2], rq_[2];
  if ((t & 63) == 0) { rs_[t >> 6] = s; rq_[t >> 6] = sq; }
  __syncthreads();
  s = rs_[0] + rs_[1]; sq = rq_[0] + rq_[1];
  const float mu = s * (1.0f / 512.0f);
  const float rstd = rsqrtf(sq * (1.0f / 512.0f) - mu * mu + 1e-5f);
  const float4 gv = ((const float4*)g)[t], bv = ((const float4*)b)[t];
  const float4 xv = ((const float4*)(x + row * 512))[t];
  float4 o;
  o.x = xv.x + (f.x - mu) * rstd * gv.x + bv.x;
  o.y = xv.y + (f.y - mu) * rstd * gv.y + bv.y;
  o.z = xv.z + (f.z - mu) * rstd * gv.z + bv.z;
  o.w = xv.w + (f.w - mu) * rstd * gv.w + bv.w;
  ((float4*)(out + row * 512))[t] = o;
}

extern "C" void kernel_launch(void* const* d_in, const int* in_sizes, int n_in,
                              void* d_out, int out_size, void* d_ws, size_t ws_size,
                              hipStream_t stream) {
  const float* x  = (const float*)d_in[0];
  const float* sc = (const float*)d_in[1];
  const float* Wq = (const float*)d_in[2];
  const float* Wk = (const float*)d_in[3];
  const float* Wv = (const float*)d_in[4];
  const float* Wm = (const float*)d_in[5];
  const float* W1 = (const float*)d_in[6];
  const float* W2 = (const float*)d_in[7];
  const float* g1 = (const float*)d_in[8];
  const float* b1 = (const float*)d_in[9];
  const float* g2 = (const float*)d_in[10];
  const float* b2 = (const float*)d_in[11];
  float* out = (float*)d_out;
  char* ws = (char*)d_ws;

  constexpr int N = 8, L = 1024, S = 4096, D = 512;
  // workspace layout (bytes); peak = 231,899,136 (~221 MB)
  u16*   h   = (u16*)(ws + 0);          // [N*L,1024] bf16: x | ln1(message)
  u16*   sb  = (u16*)(ws + 16777216);   // [N*S,512] bf16 source
  u16*   WqT = (u16*)(ws + 50331648);
  u16*   WkT = (u16*)(ws + 50855936);
  u16*   WvT = (u16*)(ws + 51380224);
  u16*   WmT = (u16*)(ws + 51904512);
  u16*   W1T = (u16*)(ws + 52428800);   // [1024,1024]
  u16*   W2T = (u16*)(ws + 54525952);   // [512,1024]
  u16*   q   = (u16*)(ws + 55574528);   // [N*L,512]
  u16*   kb  = (u16*)(ws + 63963136);   // [N*S,512]
  u16*   vb  = (u16*)(ws + 97517568);   // [N*S,512]
  u16*   vT  = (u16*)(ws + 131072000);  // [N,512,S]
  float* q2  = (float*)(ws + 164626432);
  float* k2  = (float*)(ws + 164659200);
  u16*   qk  = (u16*)(ws + 164790272);  // [N*L,S] bf16; softmaxed in place
  u16*   msg = (u16*)(ws + 55574528);   // over q (dead)
  float* mpart = (float*)(ws + 63963136); // [4][N*L,512] f32 over kb+vb (dead), 64 MB
  float* mm  = (float*)(ws + 63963136); // over partials (dead after reduce)
  u16*   hh  = (u16*)(ws + 80740352);
  float* m2  = (float*)(ws + 97517568);

  // phase 0: casts + weight transposes
  cast_x_to_h<<<dim3(4096), 256, 0, stream>>>(x, h, N * L * D / 4);
  cast_bf16<<<dim3(16384), 256, 0, stream>>>(sc, sb, N * S * D / 4);
  transpose_cast_w<<<dim3(16, 16), dim3(32, 8), 0, stream>>>(Wq, WqT, 512, 512);
  transpose_cast_w<<<dim3(16, 16), dim3(32, 8), 0, stream>>>(Wk, WkT, 512, 512);
  transpose_cast_w<<<dim3(16, 16), dim3(32, 8), 0, stream>>>(Wv, WvT, 512, 512);
  transpose_cast_w<<<dim3(16, 16), dim3(32, 8), 0, stream>>>(Wm, WmT, 512, 512);
  transpose_cast_w<<<dim3(32, 32), dim3(32, 8), 0, stream>>>(W1, W1T, 1024, 1024);
  transpose_cast_w<<<dim3(16, 32), dim3(32, 8), 0, stream>>>(W2, W2T, 1024, 512);

  // phase 1: projections
  gemm_nt<EPI_BF16><<<dim3(4, 8, 8), 256, 0, stream>>>(
      h, (size_t)L * 1024, 1024, WqT, 0, 512, q, (size_t)L * 512, 512, 512, 0);
  gemm_nt<EPI_BF16><<<dim3(4, 32, 8), 256, 0, stream>>>(
      sb, (size_t)S * 512, 512, WkT, 0, 512, kb, (size_t)S * 512, 512, 512, 0);
  gemm_nt<EPI_BF16><<<dim3(4, 32, 8), 256, 0, stream>>>(
      sb, (size_t)S * 512, 512, WvT, 0, 512, vb, (size_t)S * 512, 512, 512, 0);
  rowsumsq<<<dim3(N * L / 4), 256, 0, stream>>>(q, q2);
  rowsumsq<<<dim3(N * S / 4), 256, 0, stream>>>(kb, k2);
  transpose_v<<<dim3(64, 8, 8), dim3(64, 4), 0, stream>>>(vb, vT);

  // phase 2: attention
  gemm_nt<EPI_BF16><<<dim3(32, 8, 8), 256, 0, stream>>>(
      q, (size_t)L * 512, 512, kb, (size_t)S * 512, 512, qk, (size_t)L * S, S, 512, 0);
  softmax_inplace<<<dim3(N * L), 256, 0, stream>>>(qk, q2, k2);
  // attn·v, split-K=4: z = part*8 + batch; per-part K = 1024; fp32 partials
  gemm_nt<EPI_F32><<<dim3(4, 8, 32), 256, 0, stream>>>(
      qk, (size_t)L * S, S, vT, (size_t)D * S, S, mpart, (size_t)L * 512, 512,
      1024, (size_t)(N * L) * 512);
  reduce4_bf16<<<dim3(4096), 256, 0, stream>>>(mpart, msg);

  // phase 3: message proj + LN1 into h
  gemm_nt<EPI_F32><<<dim3(4, 8, 8), 256, 0, stream>>>(
      msg, (size_t)L * 512, 512, WmT, 0, 512, mm, (size_t)L * 512, 512, 512, 0);
  ln_to_h<<<dim3(N * L), 128, 0, stream>>>(mm, g1, b1, h);

  // phase 4: FFN
  gemm_nt<EPI_RELU_BF16><<<dim3(8, 8, 8), 256, 0, stream>>>(
      h, (size_t)L * 1024, 1024, W1T, 0, 1024, hh, (size_t)L * 1024, 1024, 1024, 0);
  gemm_nt<EPI_F32><<<dim3(4, 8, 8), 256, 0, stream>>>(
      hh, (size_t)L * 1024, 1024, W2T, 0, 1024, m2, (size_t)L * 512, 512, 1024, 0);

  // phase 5: LN2 + residual
  ln_residual<<<dim3(N * L), 128, 0, stream>>>(m2, x, g2, b2, out);
}

// Round 3
// 439.145 us; speedup vs baseline: 1.2030x; 1.2030x over previous
//
#include <hip/hip_runtime.h>
#include <stdint.h>

typedef unsigned short u16;
typedef __attribute__((ext_vector_type(8))) short bf16x8;
typedef __attribute__((ext_vector_type(4))) float f32x4;

__device__ __forceinline__ u16 f2b(float f) {
  uint32_t u = __float_as_uint(f);
  u += 0x7fffu + ((u >> 16) & 1u);
  return (u16)(u >> 16);
}
__device__ __forceinline__ float b2f(u16 h) {
  return __uint_as_float(((uint32_t)h) << 16);
}

__device__ __forceinline__ void gload_lds16(const u16* g, u16* l) {
  __builtin_amdgcn_global_load_lds(
      (const __attribute__((address_space(1))) void*)g,
      (__attribute__((address_space(3))) void*)l, 16, 0, 0);
}

// ---------------- GEMM: C[m,n] = sum_k A[m,k] * Bt[n,k] ------------------
// A: [M,K] bf16 row-major (lda), Bt: [N,K] bf16 row-major (ldb).
// 128x128 tile, BK=32, 4 waves each computing 64x64 via 4x4 MFMA 16x16x32.
// Block mapping: linear id -> batch = lin&7 (XCD colocation: all tiles of one
// batch land on one XCD so its B/A slabs stay in that XCD's L2), then
// x (fastest), y, part. gridDim.z must be 8*nparts.
// Split-K: K is the PER-PART length; C += part*pStride.
// LDS XOR swizzle kills ds_read_b128 bank conflicts (verified round 2).
enum { EPI_BF16 = 0, EPI_F32 = 1, EPI_RELU_BF16 = 2, EPI_BF16_T = 3, EPI_EXP = 4 };

template <int EPI>
__global__ __launch_bounds__(256, 2) void gemm_nt(
    const u16* __restrict__ A, size_t sA, int lda,
    const u16* __restrict__ B, size_t sB, int ldb,
    void* __restrict__ C, size_t sC, int ldc, int K, size_t pStride,
    const float* __restrict__ e_q2, const float* __restrict__ e_k2,
    float* __restrict__ e_l) {
  __shared__ __align__(16) u16 As[128 * 32];
  __shared__ __align__(16) u16 Bs[128 * 32];
  const int t = threadIdx.x;
  const int lin = blockIdx.x + gridDim.x * (blockIdx.y + gridDim.y * blockIdx.z);
  const int batch = lin & 7;
  int rest = lin >> 3;
  const int bx = rest % gridDim.x;
  const int ry = rest / gridDim.x;
  const int by = ry % gridDim.y;
  const int part = ry / gridDim.y;
  const int m0 = by * 128, n0 = bx * 128;
  const int koff = part * K;
  const u16* Ab = A + (size_t)batch * sA + (size_t)m0 * lda + koff;
  const u16* Bb = B + (size_t)batch * sB + (size_t)n0 * ldb + koff;
  // staging: thread t stages 16B at LDS slot t*16B = (row = t>>2, phys chunk t&3)
  // swizzle: that slot holds logical chunk (t&3) ^ ((t>>3)&3) of row t>>2
  const int ar0 = t >> 2;
  const int ar1 = ar0 + 64;
  const int ac0 = (((t & 3) ^ ((t >> 3) & 3)) << 3);
  const int w = t >> 6, lane = t & 63;
  const int wm = (w >> 1) << 6, wn = (w & 1) << 6;
  const int qd = lane >> 4, l16 = lane & 15;
  const int pc8 = ((qd ^ ((l16 >> 1) & 3)) << 3);  // phys chunk * 8 for reads

  f32x4 acc[4][4];
#pragma unroll
  for (int i = 0; i < 4; i++)
#pragma unroll
    for (int j = 0; j < 4; j++) acc[i][j] = (f32x4)0.0f;

  for (int k0 = 0; k0 < K; k0 += 32) {
    gload_lds16(Ab + (size_t)ar0 * lda + (k0 + ac0), As + t * 8);
    gload_lds16(Ab + (size_t)ar1 * lda + (k0 + ac0), As + (t + 256) * 8);
    gload_lds16(Bb + (size_t)ar0 * ldb + (k0 + ac0), Bs + t * 8);
    gload_lds16(Bb + (size_t)ar1 * ldb + (k0 + ac0), Bs + (t + 256) * 8);
    __syncthreads();  // drains vmcnt before barrier
    bf16x8 af[4], bfr[4];
#pragma unroll
    for (int i = 0; i < 4; i++)
      af[i] = *(const bf16x8*)(As + (wm + i * 16 + l16) * 32 + pc8);
#pragma unroll
    for (int i = 0; i < 4; i++)
      bfr[i] = *(const bf16x8*)(Bs + (wn + i * 16 + l16) * 32 + pc8);
#pragma unroll
    for (int mi = 0; mi < 4; mi++)
#pragma unroll
      for (int ni = 0; ni < 4; ni++)
        acc[mi][ni] = __builtin_amdgcn_mfma_f32_16x16x32_bf16(
            af[mi], bfr[ni], acc[mi][ni], 0, 0, 0);
    __syncthreads();
  }

  // C/D layout: col = lane&15, row = (lane>>4)*4 + r  (m89-verified)
  const size_t cbase = (size_t)part * pStride + (size_t)batch * sC;
  if (EPI == EPI_BF16_T) {
    // transposed store: C[col][row], 4 consecutive rows per lane -> ushort4
#pragma unroll
    for (int mi = 0; mi < 4; mi++) {
      const int row0 = m0 + wm + mi * 16 + qd * 4;
#pragma unroll
      for (int ni = 0; ni < 4; ni++) {
        const int col = n0 + wn + ni * 16 + l16;
        ushort4 o = make_ushort4(f2b(acc[mi][ni][0]), f2b(acc[mi][ni][1]),
                                 f2b(acc[mi][ni][2]), f2b(acc[mi][ni][3]));
        *(ushort4*)((u16*)C + cbase + (size_t)col * ldc + row0) = o;
      }
    }
  } else if (EPI == EPI_EXP) {
    // P = exp(sqrt(max(q2+k2-2*acc,0))) stored bf16; row sums -> atomicAdd(l)
    const float* q2b = e_q2 + batch * 1024;
    const float* k2b = e_k2 + (size_t)batch * 4096;
    float* lb = e_l + batch * 1024;
    float k2v[4];
#pragma unroll
    for (int ni = 0; ni < 4; ni++) k2v[ni] = k2b[n0 + wn + ni * 16 + l16];
#pragma unroll
    for (int mi = 0; mi < 4; mi++) {
      float rs[4] = {0.f, 0.f, 0.f, 0.f};
#pragma unroll
      for (int r = 0; r < 4; r++) {
        const int row = m0 + wm + mi * 16 + qd * 4 + r;
        const float q2v = q2b[row];
#pragma unroll
        for (int ni = 0; ni < 4; ni++) {
          const int col = n0 + wn + ni * 16 + l16;
          const float d2 = fmaxf(q2v + k2v[ni] - 2.0f * acc[mi][ni][r], 0.0f);
          const float p = __expf(sqrtf(d2));
          ((u16*)C)[cbase + (size_t)row * ldc + col] = f2b(p);
          rs[r] += p;
        }
      }
      // reduce rs over the 16 lanes of the l16 group (cols), then atomic
#pragma unroll
      for (int r = 0; r < 4; r++) {
#pragma unroll
        for (int off = 1; off < 16; off <<= 1) rs[r] += __shfl_xor(rs[r], off);
      }
      if (l16 == 0) {
        const int row0 = m0 + wm + mi * 16 + qd * 4;
#pragma unroll
        for (int r = 0; r < 4; r++) atomicAdd(lb + row0 + r, rs[r]);
      }
    }
  } else {
#pragma unroll
    for (int mi = 0; mi < 4; mi++) {
#pragma unroll
      for (int ni = 0; ni < 4; ni++) {
        const int col = n0 + wn + ni * 16 + l16;
#pragma unroll
        for (int r = 0; r < 4; r++) {
          const int row = m0 + wm + mi * 16 + qd * 4 + r;
          const float v = acc[mi][ni][r];
          if (EPI == EPI_F32) {
            ((float*)C)[cbase + (size_t)row * ldc + col] = v;
          } else if (EPI == EPI_RELU_BF16) {
            ((u16*)C)[cbase + (size_t)row * ldc + col] = f2b(fmaxf(v, 0.0f));
          } else {
            ((u16*)C)[cbase + (size_t)row * ldc + col] = f2b(v);
          }
        }
      }
    }
  }
}

// msg[i] = bf16((p0+p1)/l[row]) over 2 split-K fp32 partials, float4 each
__global__ __launch_bounds__(256) void reduce2_div_bf16(
    const float* __restrict__ P, const float* __restrict__ l,
    u16* __restrict__ out) {
  const size_t i = (size_t)blockIdx.x * 256 + threadIdx.x;  // float4 index
  const float4* p = (const float4*)P;
  float4 a = p[i];
  float4 b = p[i + 1048576];
  const float inv = 1.0f / l[i >> 7];
  ushort4 o = make_ushort4(f2b((a.x + b.x) * inv), f2b((a.y + b.y) * inv),
                           f2b((a.z + b.z) * inv), f2b((a.w + b.w) * inv));
  *(ushort4*)(out + (i << 2)) = o;
}

// ---------------- aux kernels ------------------
__global__ __launch_bounds__(256) void cast_x_to_h(const float* __restrict__ x,
                                                   u16* __restrict__ h, int total4) {
  int i = blockIdx.x * blockDim.x + threadIdx.x;
  if (i >= total4) return;
  const float4 f = ((const float4*)x)[i];
  int e = i << 2;
  int row = e >> 9, col = e & 511;
  ushort4 o = make_ushort4(f2b(f.x), f2b(f.y), f2b(f.z), f2b(f.w));
  *(ushort4*)(h + ((size_t)row << 10) + col) = o;
}

__global__ __launch_bounds__(256) void cast_bf16(const float* __restrict__ in,
                                                 u16* __restrict__ out, int total4) {
  int i = blockIdx.x * blockDim.x + threadIdx.x;
  if (i >= total4) return;
  const float4 f = ((const float4*)in)[i];
  ushort4 o = make_ushort4(f2b(f.x), f2b(f.y), f2b(f.z), f2b(f.w));
  *(ushort4*)(out + ((size_t)i << 2)) = o;
}

// WT[c][r] = bf16(W[r][c]);  W: [R,Cn] fp32
__global__ void transpose_cast_w(const float* __restrict__ W, u16* __restrict__ WT,
                                 int R, int Cn) {
  __shared__ float tile[32][33];
  int c0 = blockIdx.x * 32, r0 = blockIdx.y * 32;
  int tx = threadIdx.x, ty = threadIdx.y;
  for (int i = ty; i < 32; i += 8) tile[i][tx] = W[(size_t)(r0 + i) * Cn + c0 + tx];
  __syncthreads();
  for (int i = ty; i < 32; i += 8) WT[(size_t)(c0 + i) * R + r0 + tx] = f2b(tile[tx][i]);
}

// out[row] = sum_c X[row][c]^2   (X bf16, 512 cols, one wave per row)
__global__ __launch_bounds__(256) void rowsumsq(const u16* __restrict__ X,
                                                float* __restrict__ out) {
  const int w = threadIdx.x >> 6, lane = threadIdx.x & 63;
  const size_t row = (size_t)blockIdx.x * 4 + w;
  const u16* xr = X + row * 512 + lane * 8;
  float s = 0.f;
#pragma unroll
  for (int i = 0; i < 8; i++) { float v = b2f(xr[i]); s += v * v; }
#pragma unroll
  for (int off = 32; off; off >>= 1) s += __shfl_xor(s, off);
  if (lane == 0) out[row] = s;
}

// h[row][512..1023] = bf16(LN(mm[row]; g,b)); 128 thr/row, float4 each
__global__ __launch_bounds__(128) void ln_to_h(const float* __restrict__ mm,
                                               const float* __restrict__ g,
                                               const float* __restrict__ b,
                                               u16* __restrict__ h) {
  const size_t row = blockIdx.x;
  const int t = threadIdx.x;
  const float4 f = ((const float4*)(mm + row * 512))[t];
  float s = f.x + f.y + f.z + f.w;
  float sq = f.x * f.x + f.y * f.y + f.z * f.z + f.w * f.w;
#pragma unroll
  for (int off = 32; off; off >>= 1) { s += __shfl_xor(s, off); sq += __shfl_xor(sq, off); }
  __shared__ float rs_[2], rq_[2];
  if ((t & 63) == 0) { rs_[t >> 6] = s; rq_[t >> 6] = sq; }
  __syncthreads();
  s = rs_[0] + rs_[1]; sq = rq_[0] + rq_[1];
  const float mu = s * (1.0f / 512.0f);
  const float rstd = rsqrtf(sq * (1.0f / 512.0f) - mu * mu + 1e-5f);
  const float4 gv = ((const float4*)g)[t], bv = ((const float4*)b)[t];
  ushort4 o = make_ushort4(f2b((f.x - mu) * rstd * gv.x + bv.x),
                           f2b((f.y - mu) * rstd * gv.y + bv.y),
                           f2b((f.z - mu) * rstd * gv.z + bv.z),
                           f2b((f.w - mu) * rstd * gv.w + bv.w));
  *(ushort4*)(h + (row << 10) + 512 + (t << 2)) = o;
}

// out[row] = x[row] + LN(m2[row]; g,b)
__global__ __launch_bounds__(128) void ln_residual(const float* __restrict__ m2,
                                                   const float* __restrict__ x,
                                                   const float* __restrict__ g,
                                                   const float* __restrict__ b,
                                                   float* __restrict__ out) {
  const size_t row = blockIdx.x;
  const int t = threadIdx.x;
  const float4 f = ((const float4*)(m2 + row * 512))[t];
  float s = f.x + f.y + f.z + f.w;
  float sq = f.x * f.x + f.y * f.y + f.z * f.z + f.w * f.w;
#pragma unroll
  for (int off = 32; off; off >>= 1) { s += __shfl_xor(s, off); sq += __shfl_xor(sq, off); }
  __shared__ float rs_[2], rq_[2];
  if ((t & 63) == 0) { rs_[t >> 6] = s; rq_[t >> 6] = sq; }
  __syncthreads();
  s = rs_[0] + rs_[1]; sq = rq_[0] + rq_[1];
  const float mu = s * (1.0f / 512.0f);
  const float rstd = rsqrtf(sq * (1.0f / 512.0f) - mu * mu + 1e-5f);
  const float4 gv = ((const float4*)g)[t], bv = ((const float4*)b)[t];
  const float4 xv = ((const float4*)(x + row * 512))[t];
  float4 o;
  o.x = xv.x + (f.x - mu) * rstd * gv.x + bv.x;
  o.y = xv.y + (f.y - mu) * rstd * gv.y + bv.y;
  o.z = xv.z + (f.z - mu) * rstd * gv.z + bv.z;
  o.w = xv.w + (f.w - mu) * rstd * gv.w + bv.w;
  ((float4*)(out + row * 512))[t] = o;
}

extern "C" void kernel_launch(void* const* d_in, const int* in_sizes, int n_in,
                              void* d_out, int out_size, void* d_ws, size_t ws_size,
                              hipStream_t stream) {
  const float* x  = (const float*)d_in[0];
  const float* sc = (const float*)d_in[1];
  const float* Wq = (const float*)d_in[2];
  const float* Wk = (const float*)d_in[3];
  const float* Wv = (const float*)d_in[4];
  const float* Wm = (const float*)d_in[5];
  const float* W1 = (const float*)d_in[6];
  const float* W2 = (const float*)d_in[7];
  const float* g1 = (const float*)d_in[8];
  const float* b1 = (const float*)d_in[9];
  const float* g2 = (const float*)d_in[10];
  const float* b2 = (const float*)d_in[11];
  float* out = (float*)d_out;
  char* ws = (char*)d_ws;

  constexpr int N = 8, L = 1024, S = 4096, D = 512;
  // workspace layout (bytes); peak = 231,899,136 (~221 MB)
  u16*   h   = (u16*)(ws + 0);          // [N*L,1024] bf16: x | ln1(message)
  u16*   sb  = (u16*)(ws + 16777216);   // [N*S,512] bf16 source
  u16*   WqT = (u16*)(ws + 50331648);
  u16*   WkT = (u16*)(ws + 50855936);
  u16*   WvT = (u16*)(ws + 51380224);
  u16*   WmT = (u16*)(ws + 51904512);
  u16*   W1T = (u16*)(ws + 52428800);   // [1024,1024]
  u16*   W2T = (u16*)(ws + 54525952);   // [512,1024]
  u16*   q   = (u16*)(ws + 55574528);   // [N*L,512]
  u16*   kb  = (u16*)(ws + 63963136);   // [N*S,512] (dead after qk gemm)
  u16*   vT  = (u16*)(ws + 97517568);   // [N][512,S] bf16 (v written transposed)
  float* lsum= (float*)(ws + 131072000);// [N*L] fp32 row sums of P
  float* q2  = (float*)(ws + 164626432);
  float* k2  = (float*)(ws + 164659200);
  u16*   qk  = (u16*)(ws + 164790272);  // [N*L,S] bf16 P = exp(dist), unnormalized
  u16*   msg = (u16*)(ws + 55574528);   // over q (dead after qk)
  float* mpart = (float*)(ws + 63963136); // [2][N*L,512] f32 over kb (dead), 32 MB
  float* mm  = (float*)(ws + 63963136); // over mpart (dead after reduce)
  u16*   hh  = (u16*)(ws + 80740352);   // 16 MB
  float* m2  = (float*)(ws + 97517568); // over vT (dead after attn.v)

  // phase 0: casts + weight transposes
  cast_x_to_h<<<dim3(4096), 256, 0, stream>>>(x, h, N * L * D / 4);
  cast_bf16<<<dim3(16384), 256, 0, stream>>>(sc, sb, N * S * D / 4);
  transpose_cast_w<<<dim3(16, 16), dim3(32, 8), 0, stream>>>(Wq, WqT, 512, 512);
  transpose_cast_w<<<dim3(16, 16), dim3(32, 8), 0, stream>>>(Wk, WkT, 512, 512);
  transpose_cast_w<<<dim3(16, 16), dim3(32, 8), 0, stream>>>(Wv, WvT, 512, 512);
  transpose_cast_w<<<dim3(16, 16), dim3(32, 8), 0, stream>>>(Wm, WmT, 512, 512);
  transpose_cast_w<<<dim3(32, 32), dim3(32, 8), 0, stream>>>(W1, W1T, 1024, 1024);
  transpose_cast_w<<<dim3(16, 32), dim3(32, 8), 0, stream>>>(W2, W2T, 1024, 512);

  // phase 1: projections (v written pre-transposed)
  gemm_nt<EPI_BF16><<<dim3(4, 8, 8), 256, 0, stream>>>(
      h, (size_t)L * 1024, 1024, WqT, 0, 512, q, (size_t)L * 512, 512, 512, 0,
      nullptr, nullptr, nullptr);
  gemm_nt<EPI_BF16><<<dim3(4, 32, 8), 256, 0, stream>>>(
      sb, (size_t)S * 512, 512, WkT, 0, 512, kb, (size_t)S * 512, 512, 512, 0,
      nullptr, nullptr, nullptr);
  gemm_nt<EPI_BF16_T><<<dim3(4, 32, 8), 256, 0, stream>>>(
      sb, (size_t)S * 512, 512, WvT, 0, 512, vT, (size_t)D * S, S, 512, 0,
      nullptr, nullptr, nullptr);
  rowsumsq<<<dim3(N * L / 4), 256, 0, stream>>>(q, q2);
  rowsumsq<<<dim3(N * S / 4), 256, 0, stream>>>(kb, k2);
  hipMemsetAsync(lsum, 0, (size_t)N * L * sizeof(float), stream);

  // phase 2: attention. qk gemm fuses exp(dist) + row-sum accumulation;
  // attn.v (split-K=2) consumes unnormalized P; reduce divides by lsum.
  gemm_nt<EPI_EXP><<<dim3(32, 8, 8), 256, 0, stream>>>(
      q, (size_t)L * 512, 512, kb, (size_t)S * 512, 512, qk, (size_t)L * S, S,
      512, 0, q2, k2, lsum);
  gemm_nt<EPI_F32><<<dim3(4, 8, 16), 256, 0, stream>>>(
      qk, (size_t)L * S, S, vT, (size_t)D * S, S, mpart, (size_t)L * 512, 512,
      2048, (size_t)(N * L) * 512, nullptr, nullptr, nullptr);
  reduce2_div_bf16<<<dim3(4096), 256, 0, stream>>>(mpart, lsum, msg);

  // phase 3: message proj + LN1 into h
  gemm_nt<EPI_F32><<<dim3(4, 8, 8), 256, 0, stream>>>(
      msg, (size_t)L * 512, 512, WmT, 0, 512, mm, (size_t)L * 512, 512, 512, 0,
      nullptr, nullptr, nullptr);
  ln_to_h<<<dim3(N * L), 128, 0, stream>>>(mm, g1, b1, h);

  // phase 4: FFN
  gemm_nt<EPI_RELU_BF16><<<dim3(8, 8, 8), 256, 0, stream>>>(
      h, (size_t)L * 1024, 1024, W1T, 0, 1024, hh, (size_t)L * 1024, 1024, 1024,
      0, nullptr, nullptr, nullptr);
  gemm_nt<EPI_F32><<<dim3(4, 8, 8), 256, 0, stream>>>(
      hh, (size_t)L * 1024, 1024, W2T, 0, 1024, m2, (size_t)L * 512, 512, 1024,
      0, nullptr, nullptr, nullptr);

  // phase 5: LN2 + residual
  ln_residual<<<dim3(N * L), 128, 0, stream>>>(m2, x, g2, b2, out);
}